// Round 5
// baseline (163.454 us; speedup 1.0000x reference)
//
#include <hip/hip_runtime.h>
#include <cstdint>
#include <cstddef>

#define NEG_FILL -1000000.0f

// One WAVE per row; 4 rows per 256-thread block. No LDS, no barriers, no
// atomics in the row kernel. lined[256]/match[256] are register-resident
// (4 values per lane: class c = k*64 + lane). Rank bookkeeping is done on
// wave-uniform ballot masks (SALU); the matched-cell scatter is a
// wave-uniform rare branch (~0.2 matches per row on this data).
__global__ __launch_bounds__(256) void criterion_rows(
    const float* __restrict__ pred_legal,
    const float* __restrict__ pred_quality,
    const float* __restrict__ target_legal,
    const float* __restrict__ target_quality,
    float* __restrict__ partials, int B) {

    const int tid  = threadIdx.x;
    const int lane = tid & 63;
    const int w    = tid >> 6;
    const int row  = blockIdx.x * 4 + w;
    if (row >= B) return;

    const float* __restrict__ xrow  = pred_legal     + (size_t)row * 4096;
    const float* __restrict__ trow  = target_legal   + (size_t)row * 4096;
    const float* __restrict__ pqrow = pred_quality   + (size_t)row * 256;
    const float* __restrict__ tqrow = target_quality + (size_t)row * 256;

    // register-resident lined/match: class c = k*64 + lane
    float vs[4] = {NEG_FILL, NEG_FILL, NEG_FILL, NEG_FILL};
    float mk[4] = {0.0f, 0.0f, 0.0f, 0.0f};

    float bce = 0.0f;
    int t_run = 0, p_run = 0;

    // 4-deep load prefetch ring: 8 outstanding float4 loads
    float4 xb[4], tb[4];
    #pragma unroll
    for (int i = 0; i < 4; ++i) {
        xb[i] = *(const float4*)(xrow + i * 256 + lane * 4);
        tb[i] = *(const float4*)(trow + i * 256 + lane * 4);
    }

    #pragma unroll
    for (int seg = 0; seg < 16; ++seg) {
        const float4 x4 = xb[seg & 3];
        const float4 t4 = tb[seg & 3];
        if (seg + 4 < 16) {
            xb[seg & 3] = *(const float4*)(xrow + (seg + 4) * 256 + lane * 4);
            tb[seg & 3] = *(const float4*)(trow + (seg + 4) * 256 + lane * 4);
        }
        const float xs[4] = {x4.x, x4.y, x4.z, x4.w};
        const float ts[4] = {t4.x, t4.y, t4.z, t4.w};

        uint64_t bt[4], bp[4];
        #pragma unroll
        for (int e = 0; e < 4; ++e) {
            const float x = xs[e], t = ts[e];
            // L = log1p(exp(-|x|)) via exp2/log2 (abs err ~1e-7, thr 1.28)
            const float a  = __builtin_fabsf(x);
            const float p2 = __builtin_amdgcn_exp2f(a * -1.44269504f);
            const float L  = __builtin_amdgcn_logf(1.0f + p2) * 0.69314718f;
            const float relu = fmaxf(x, 0.0f);
            const float wgt  = 0.25f + 0.75f * t;          // t in {0,1}
            bce += wgt * (relu - x * t + L);
            bt[e] = __ballot(t == 1.0f);
            bp[e] = __ballot(x > 0.0f);
        }

        const uint64_t bm0 = bt[0] & bp[0], bm1 = bt[1] & bp[1];
        const uint64_t bm2 = bt[2] & bp[2], bm3 = bt[3] & bp[3];
        if ((bm0 | bm1 | bm2 | bm3) != 0ull) {     // wave-uniform rare branch
            const uint64_t bms[4] = {bm0, bm1, bm2, bm3};
            #pragma unroll
            for (int e = 0; e < 4; ++e) {
                uint64_t m = bms[e];
                while (m) {                         // uniform loop over matches
                    const int j = (int)__builtin_ctzll(m);
                    m &= m - 1;
                    const uint64_t below = (j == 0) ? 0ull : ((~0ull) >> (64 - j));
                    int tr = t_run, pr = p_run;
                    #pragma unroll
                    for (int e2 = 0; e2 < 4; ++e2) {
                        tr += (int)__popcll(bt[e2] & below);
                        pr += (int)__popcll(bp[e2] & below);
                        if (e2 < e) {
                            tr += (int)((bt[e2] >> j) & 1ull);
                            pr += (int)((bp[e2] >> j) & 1ull);
                        }
                    }
                    if (tr < 256 && pr < 255) {
                        const float v = pqrow[pr];      // uniform address
                        const int tslot = tr >> 6, tlane = tr & 63;
                        const bool hit = (lane == tlane);
                        #pragma unroll
                        for (int k = 0; k < 4; ++k) {
                            if (k == tslot) {           // uniform select
                                vs[k] = hit ? v    : vs[k];
                                mk[k] = hit ? 1.0f : mk[k];
                            }
                        }
                    }
                }
            }
        }
        t_run += (int)(__popcll(bt[0]) + __popcll(bt[1])
                     + __popcll(bt[2]) + __popcll(bt[3]));
        p_run += (int)(__popcll(bp[0]) + __popcll(bp[1])
                     + __popcll(bp[2]) + __popcll(bp[3]));
    }

    // ---- CE over classes [0,255) + MSE on class 255, all in-wave ----
    float tq[4];
    #pragma unroll
    for (int k = 0; k < 4; ++k)
        tq[k] = tqrow[k * 64 + lane] * mk[k];
    // exclude class 255 (k=3, lane 63)
    if (lane == 63) { vs[3] = -3.0e38f; tq[3] = 0.0f; }

    float m = fmaxf(fmaxf(vs[0], vs[1]), fmaxf(vs[2], vs[3]));
    #pragma unroll
    for (int off = 32; off > 0; off >>= 1)
        m = fmaxf(m, __shfl_xor(m, off, 64));

    float s1 = 0.0f, s2 = 0.0f, s3 = 0.0f;
    #pragma unroll
    for (int k = 0; k < 4; ++k) {
        s1 += __builtin_amdgcn_exp2f((vs[k] - m) * 1.44269504f);
        s2 += tq[k];
        s3 += tq[k] * vs[k];
    }
    // vs[3]=-3e38 lane63: exp underflows to 0; tq zeroed. handle m=-3e38 never
    float s0 = bce;
    #pragma unroll
    for (int off = 32; off > 0; off >>= 1) {
        s0 += __shfl_xor(s0, off, 64);
        s1 += __shfl_xor(s1, off, 64);
        s2 += __shfl_xor(s2, off, 64);
        s3 += __shfl_xor(s3, off, 64);
    }

    if (lane == 0) {
        const float lse  = m + __builtin_amdgcn_logf(s1) * 0.69314718f;
        // sum_c -(tq_c/(tsum+eps))*(v_c - lse) = -(tv - lse*tsum)/(tsum+eps)
        const float csum = -(s3 - lse * s2) / (s2 + 1e-10f);
        const float d    = pqrow[255] - tqrow[255];
        float4 o;
        o.x = s0; o.y = csum; o.z = d * d; o.w = 0.0f;
        *(float4*)(partials + (size_t)row * 4) = o;
    }
}

__global__ __launch_bounds__(256) void finalize_kernel(
    const float* __restrict__ partials, float* __restrict__ out, int B) {
    const int tid = threadIdx.x;
    double s0 = 0.0, s1 = 0.0, s2 = 0.0;
    for (int r = tid; r < B; r += 256) {
        const float4 p = *(const float4*)(partials + (size_t)r * 4);
        s0 += (double)p.x; s1 += (double)p.y; s2 += (double)p.z;
    }
    #pragma unroll
    for (int off = 32; off > 0; off >>= 1) {
        s0 += __shfl_xor(s0, off, 64);
        s1 += __shfl_xor(s1, off, 64);
        s2 += __shfl_xor(s2, off, 64);
    }
    __shared__ double red[3][4];
    const int lane = tid & 63, w = tid >> 6;
    if (lane == 0) { red[0][w] = s0; red[1][w] = s1; red[2][w] = s2; }
    __syncthreads();
    if (tid == 0) {
        const double bs = red[0][0] + red[0][1] + red[0][2] + red[0][3];
        const double cs = red[1][0] + red[1][1] + red[1][2] + red[1][3];
        const double qs = red[2][0] + red[2][1] + red[2][2] + red[2][3];
        out[0] = (float)(bs / ((double)B * 4096.0));
        out[1] = (float)(200.0 * (cs / 255.0) + qs / (double)B);
    }
}

extern "C" void kernel_launch(void* const* d_in, const int* in_sizes, int n_in,
                              void* d_out, int out_size, void* d_ws, size_t ws_size,
                              hipStream_t stream) {
    const float* pred_legal     = (const float*)d_in[0];
    const float* pred_quality   = (const float*)d_in[1];
    const float* target_legal   = (const float*)d_in[2];
    const float* target_quality = (const float*)d_in[3];

    const int B = in_sizes[0] / 4096;   // 4096

    float* partials = (float*)d_ws;     // B * 4 floats

    const int grid = (B + 3) / 4;
    criterion_rows<<<grid, 256, 0, stream>>>(
        pred_legal, pred_quality, target_legal, target_quality, partials, B);
    finalize_kernel<<<1, 256, 0, stream>>>(partials, (float*)d_out, B);
}

// Round 6
// 162.439 us; speedup vs baseline: 1.0063x; 1.0063x over previous
//
#include <hip/hip_runtime.h>
#include <cstdint>
#include <cstddef>

#define NEG_FILL -1000000.0f

// Two waves per row (half-row each), 2 rows per 256-thread block.
// Phase 1: each wave fully prefetches its 2048-cell half (16 float4 loads in
// flight), computes BCE + ballot masks, collects rare matched cells as
// wave-uniform (ltr,lpr) entries in LDS. Phase 2 (1 barrier): exchange per-wave
// t/p counts, replay entries with globalized ranks into LDS lined/match.
// Phase 3: half-0 wave computes the row CE/MSE entirely in-wave (R5 math).
__global__ __launch_bounds__(256, 4) void criterion_rows(
    const float* __restrict__ pred_legal,
    const float* __restrict__ pred_quality,
    const float* __restrict__ target_legal,
    const float* __restrict__ target_quality,
    float* __restrict__ partials, int B) {

    const int tid  = threadIdx.x;
    const int lane = tid & 63;
    const int w    = tid >> 6;
    const int rloc = w >> 1;          // row-in-block: 0/1
    const int half = w & 1;           // half-row: 0/1
    const int row_raw = blockIdx.x * 2 + rloc;
    const bool active = row_raw < B;
    const int row = active ? row_raw : (B - 1);

    __shared__ float lined[2][256];
    __shared__ float matchv[2][256];
    __shared__ int   scnt[4][3];      // per wave: t_run, p_run, nm
    __shared__ float sbce[4];
    __shared__ int   sent[4][8];      // packed entries: (ltr<<8)|lpr

    { // init LDS (covered by the phase-1 barrier)
        float* lp = &lined[0][0];
        float* mp = &matchv[0][0];
        lp[tid] = NEG_FILL; lp[tid + 256] = NEG_FILL;
        mp[tid] = 0.0f;     mp[tid + 256] = 0.0f;
    }

    const float* __restrict__ xrow  = pred_legal     + (size_t)row * 4096 + half * 2048;
    const float* __restrict__ trow  = target_legal   + (size_t)row * 4096 + half * 2048;
    const float* __restrict__ pqrow = pred_quality   + (size_t)row * 256;
    const float* __restrict__ tqrow = target_quality + (size_t)row * 256;

    // ---- Phase 1: full prefetch of the half-row (16 loads in flight) ----
    float4 xb[8], tb[8];
    #pragma unroll
    for (int i = 0; i < 8; ++i) {
        xb[i] = *(const float4*)(xrow + i * 256 + lane * 4);
        tb[i] = *(const float4*)(trow + i * 256 + lane * 4);
    }

    float bce = 0.0f;
    int t_run = 0, p_run = 0, nm = 0;

    #pragma unroll
    for (int seg = 0; seg < 8; ++seg) {
        const float4 x4 = xb[seg];
        const float4 t4 = tb[seg];
        const float xs[4] = {x4.x, x4.y, x4.z, x4.w};
        const float ts[4] = {t4.x, t4.y, t4.z, t4.w};

        uint64_t bt[4], bp[4];
        #pragma unroll
        for (int e = 0; e < 4; ++e) {
            const float x = xs[e], t = ts[e];
            const float a  = __builtin_fabsf(x);
            const float p2 = __builtin_amdgcn_exp2f(a * -1.44269504f);
            const float L  = __builtin_amdgcn_logf(1.0f + p2) * 0.69314718f;
            const float relu = fmaxf(x, 0.0f);
            const float wgt  = 0.25f + 0.75f * t;          // t in {0,1}
            bce += wgt * (relu - x * t + L);
            bt[e] = __ballot(t == 1.0f);
            bp[e] = __ballot(x > 0.0f);
        }

        const uint64_t bm0 = bt[0] & bp[0], bm1 = bt[1] & bp[1];
        const uint64_t bm2 = bt[2] & bp[2], bm3 = bt[3] & bp[3];
        if ((bm0 | bm1 | bm2 | bm3) != 0ull) {     // wave-uniform rare branch
            const uint64_t bms[4] = {bm0, bm1, bm2, bm3};
            #pragma unroll
            for (int e = 0; e < 4; ++e) {
                uint64_t m = bms[e];
                while (m) {                         // uniform loop over matches
                    const int j = (int)__builtin_ctzll(m);
                    m &= m - 1;
                    const uint64_t below = (j == 0) ? 0ull : ((~0ull) >> (64 - j));
                    int ltr = t_run, lpr = p_run;
                    #pragma unroll
                    for (int e2 = 0; e2 < 4; ++e2) {
                        ltr += (int)__popcll(bt[e2] & below);
                        lpr += (int)__popcll(bp[e2] & below);
                        if (e2 < e) {
                            ltr += (int)((bt[e2] >> j) & 1ull);
                            lpr += (int)((bp[e2] >> j) & 1ull);
                        }
                    }
                    // local filter: global rank >= local rank
                    if (ltr < 256 && lpr < 255 && nm < 8) {
                        if (lane == 0) sent[w][nm] = (ltr << 8) | lpr;
                        ++nm;                       // uniform
                    }
                }
            }
        }
        t_run += (int)(__popcll(bt[0]) + __popcll(bt[1])
                     + __popcll(bt[2]) + __popcll(bt[3]));
        p_run += (int)(__popcll(bp[0]) + __popcll(bp[1])
                     + __popcll(bp[2]) + __popcll(bp[3]));
    }

    // wave-reduce bce
    #pragma unroll
    for (int off = 32; off > 0; off >>= 1)
        bce += __shfl_xor(bce, off, 64);

    if (lane == 0) {
        scnt[w][0] = t_run; scnt[w][1] = p_run; scnt[w][2] = nm;
        sbce[w] = bce;
    }
    __syncthreads();

    // ---- Phase 2: globalize ranks, scatter rare entries into LDS ----
    {
        const int w0 = rloc * 2;                 // half-0 wave of this row
        int baseT = 0, baseP = 0;
        if (half == 1) { baseT = scnt[w0][0]; baseP = scnt[w0][1]; }
        const int mynm = scnt[w][2];
        for (int i = 0; i < mynm; ++i) {         // uniform, rare
            const int ent = sent[w][i];
            const int tr = baseT + (ent >> 8);
            const int pr = baseP + (ent & 0xFF);
            if (tr < 256 && pr < 255) {
                if (lane == 0) {
                    lined[rloc][tr]  = pqrow[pr];
                    matchv[rloc][tr] = 1.0f;
                }
            }
        }
    }
    __syncthreads();

    // ---- Phase 3: CE over classes [0,255) + MSE, by the half-0 wave ----
    if (half == 0) {
        float vs[4], tq[4];
        #pragma unroll
        for (int k = 0; k < 4; ++k) {
            const int c = k * 64 + lane;
            vs[k] = lined[rloc][c];
            tq[k] = tqrow[c] * matchv[rloc][c];
        }
        if (lane == 63) { vs[3] = -3.0e38f; tq[3] = 0.0f; }  // class 255

        float m = fmaxf(fmaxf(vs[0], vs[1]), fmaxf(vs[2], vs[3]));
        #pragma unroll
        for (int off = 32; off > 0; off >>= 1)
            m = fmaxf(m, __shfl_xor(m, off, 64));

        float s1 = 0.0f, s2 = 0.0f, s3 = 0.0f;
        #pragma unroll
        for (int k = 0; k < 4; ++k) {
            s1 += __builtin_amdgcn_exp2f((vs[k] - m) * 1.44269504f);
            s2 += tq[k];
            s3 += tq[k] * vs[k];
        }
        #pragma unroll
        for (int off = 32; off > 0; off >>= 1) {
            s1 += __shfl_xor(s1, off, 64);
            s2 += __shfl_xor(s2, off, 64);
            s3 += __shfl_xor(s3, off, 64);
        }

        if (lane == 0 && active) {
            const float s0   = sbce[w] + sbce[w + 1];
            const float lse  = m + __builtin_amdgcn_logf(s1) * 0.69314718f;
            const float csum = -(s3 - lse * s2) / (s2 + 1e-10f);
            const float d    = pqrow[255] - tqrow[255];
            float4 o;
            o.x = s0; o.y = csum; o.z = d * d; o.w = 0.0f;
            *(float4*)(partials + (size_t)row * 4) = o;
        }
    }
}

__global__ __launch_bounds__(256) void finalize_kernel(
    const float* __restrict__ partials, float* __restrict__ out, int B) {
    const int tid = threadIdx.x;
    double s0 = 0.0, s1 = 0.0, s2 = 0.0;
    for (int r = tid; r < B; r += 256) {
        const float4 p = *(const float4*)(partials + (size_t)r * 4);
        s0 += (double)p.x; s1 += (double)p.y; s2 += (double)p.z;
    }
    #pragma unroll
    for (int off = 32; off > 0; off >>= 1) {
        s0 += __shfl_xor(s0, off, 64);
        s1 += __shfl_xor(s1, off, 64);
        s2 += __shfl_xor(s2, off, 64);
    }
    __shared__ double red[3][4];
    const int lane = tid & 63, w = tid >> 6;
    if (lane == 0) { red[0][w] = s0; red[1][w] = s1; red[2][w] = s2; }
    __syncthreads();
    if (tid == 0) {
        const double bs = red[0][0] + red[0][1] + red[0][2] + red[0][3];
        const double cs = red[1][0] + red[1][1] + red[1][2] + red[1][3];
        const double qs = red[2][0] + red[2][1] + red[2][2] + red[2][3];
        out[0] = (float)(bs / ((double)B * 4096.0));
        out[1] = (float)(200.0 * (cs / 255.0) + qs / (double)B);
    }
}

extern "C" void kernel_launch(void* const* d_in, const int* in_sizes, int n_in,
                              void* d_out, int out_size, void* d_ws, size_t ws_size,
                              hipStream_t stream) {
    const float* pred_legal     = (const float*)d_in[0];
    const float* pred_quality   = (const float*)d_in[1];
    const float* target_legal   = (const float*)d_in[2];
    const float* target_quality = (const float*)d_in[3];

    const int B = in_sizes[0] / 4096;   // 4096

    float* partials = (float*)d_ws;     // B * 4 floats

    const int grid = (B + 1) / 2;
    criterion_rows<<<grid, 256, 0, stream>>>(
        pred_legal, pred_quality, target_legal, target_quality, partials, B);
    finalize_kernel<<<1, 256, 0, stream>>>(partials, (float*)d_out, B);
}

// Round 7
// 158.145 us; speedup vs baseline: 1.0336x; 1.0272x over previous
//
#include <hip/hip_runtime.h>
#include <cstdint>
#include <cstddef>

#define NEG_FILL -1000000.0f

// async global->LDS DMA: zero VGPR cost, compiler cannot sink/serialize it.
// LDS dest is wave-uniform base; HW scatters lane i at base + i*16 bytes.
__device__ __forceinline__ void load16_to_lds(const float* g, float* l) {
    auto g1 = (const __attribute__((address_space(1))) void*)g;
    auto l3 = (__attribute__((address_space(3))) void*)(uint32_t)(uintptr_t)l;
    __builtin_amdgcn_global_load_lds(g1, l3, 16, 0, 0);
}

// One BLOCK per row (4 waves, wave w owns quarter [w*1024, (w+1)*1024)).
// Phase 0: 32 async DMAs stage x/t row halves into LDS (32 KB in flight).
// Phase 1: R6-proven ballot/rank math, reading from LDS.
// Phase 2: cross-wave rank globalization + rare-entry scatter.
// Phase 3: wave 0 computes CE/MSE (R5/R6-verified math).
__global__ __launch_bounds__(256) void criterion_rows(
    const float* __restrict__ pred_legal,
    const float* __restrict__ pred_quality,
    const float* __restrict__ target_legal,
    const float* __restrict__ target_quality,
    float* __restrict__ partials, int B) {

    const int b    = blockIdx.x;
    const int tid  = threadIdx.x;
    const int lane = tid & 63;
    const int w    = tid >> 6;

    __shared__ __align__(16) float xs[4096];
    __shared__ __align__(16) float ts[4096];
    __shared__ float lined[256];
    __shared__ float matchv[256];
    __shared__ int   scnt_t[4], scnt_p[4];
    __shared__ float sbce[4];
    __shared__ int   sent[4][8];      // packed entries: (ltr<<8)|lpr

    const float* __restrict__ xrow  = pred_legal     + (size_t)b * 4096;
    const float* __restrict__ trow  = target_legal   + (size_t)b * 4096;
    const float* __restrict__ pqrow = pred_quality   + (size_t)b * 256;
    const float* __restrict__ tqrow = target_quality + (size_t)b * 256;

    // ---- Phase 0: stage quarter-row per wave, 8 DMAs each, all in flight ----
    #pragma unroll
    for (int i = 0; i < 4; ++i) {
        const int off = w * 1024 + i * 256;            // floats, wave-uniform
        load16_to_lds(xrow + off + lane * 4, &xs[off]);
        load16_to_lds(trow + off + lane * 4, &ts[off]);
    }
    lined[tid]  = NEG_FILL;                            // overlap with DMA
    matchv[tid] = 0.0f;
    __syncthreads();                                   // drains vmcnt + barrier

    // ---- Phase 1: BCE + ballot ranks over the quarter (from LDS) ----
    float bce = 0.0f;
    int t_run = 0, p_run = 0, nm = 0;

    #pragma unroll
    for (int seg = 0; seg < 4; ++seg) {
        const int base = w * 1024 + seg * 256 + lane * 4;
        const float4 x4 = *(const float4*)&xs[base];
        const float4 t4 = *(const float4*)&ts[base];
        const float xv[4] = {x4.x, x4.y, x4.z, x4.w};
        const float tv[4] = {t4.x, t4.y, t4.z, t4.w};

        uint64_t bt[4], bp[4];
        #pragma unroll
        for (int e = 0; e < 4; ++e) {
            const float x = xv[e], t = tv[e];
            const float a  = __builtin_fabsf(x);
            const float p2 = __builtin_amdgcn_exp2f(a * -1.44269504f);
            const float L  = __builtin_amdgcn_logf(1.0f + p2) * 0.69314718f;
            const float relu = fmaxf(x, 0.0f);
            const float wgt  = 0.25f + 0.75f * t;      // t in {0,1}
            bce += wgt * (relu - x * t + L);
            bt[e] = __ballot(t == 1.0f);
            bp[e] = __ballot(x > 0.0f);
        }

        const uint64_t bm0 = bt[0] & bp[0], bm1 = bt[1] & bp[1];
        const uint64_t bm2 = bt[2] & bp[2], bm3 = bt[3] & bp[3];
        if ((bm0 | bm1 | bm2 | bm3) != 0ull) {         // wave-uniform, rare
            const uint64_t bms[4] = {bm0, bm1, bm2, bm3};
            #pragma unroll
            for (int e = 0; e < 4; ++e) {
                uint64_t m = bms[e];
                while (m) {                            // uniform match loop
                    const int j = (int)__builtin_ctzll(m);
                    m &= m - 1;
                    const uint64_t below = (j == 0) ? 0ull : ((~0ull) >> (64 - j));
                    int ltr = t_run, lpr = p_run;
                    #pragma unroll
                    for (int e2 = 0; e2 < 4; ++e2) {
                        ltr += (int)__popcll(bt[e2] & below);
                        lpr += (int)__popcll(bp[e2] & below);
                        if (e2 < e) {
                            ltr += (int)((bt[e2] >> j) & 1ull);
                            lpr += (int)((bp[e2] >> j) & 1ull);
                        }
                    }
                    // local filter: global rank >= local rank
                    if (ltr < 256 && lpr < 255 && nm < 8) {
                        if (lane == 0) sent[w][nm] = (ltr << 8) | lpr;
                        ++nm;                          // uniform
                    }
                }
            }
        }
        t_run += (int)(__popcll(bt[0]) + __popcll(bt[1])
                     + __popcll(bt[2]) + __popcll(bt[3]));
        p_run += (int)(__popcll(bp[0]) + __popcll(bp[1])
                     + __popcll(bp[2]) + __popcll(bp[3]));
    }

    #pragma unroll
    for (int off = 32; off > 0; off >>= 1)
        bce += __shfl_xor(bce, off, 64);
    if (lane == 0) {
        scnt_t[w] = t_run; scnt_p[w] = p_run; sbce[w] = bce;
    }
    __syncthreads();

    // ---- Phase 2: globalize ranks, scatter rare entries ----
    {
        int baseT = 0, baseP = 0;
        #pragma unroll
        for (int k = 0; k < 4; ++k)
            if (k < w) { baseT += scnt_t[k]; baseP += scnt_p[k]; }
        for (int i = 0; i < nm; ++i) {                 // uniform, rare
            const int ent = sent[w][i];
            const int tr = baseT + (ent >> 8);
            const int pr = baseP + (ent & 0xFF);
            if (tr < 256 && pr < 255 && lane == 0) {
                lined[tr]  = pqrow[pr];                // t-ranks unique
                matchv[tr] = 1.0f;
            }
        }
    }
    __syncthreads();

    // ---- Phase 3: CE over classes [0,255) + MSE on 255, wave 0 ----
    if (w == 0) {
        float vs[4], tq[4];
        #pragma unroll
        for (int k = 0; k < 4; ++k) {
            const int c = k * 64 + lane;
            vs[k] = lined[c];
            tq[k] = tqrow[c] * matchv[c];
        }
        if (lane == 63) { vs[3] = -3.0e38f; tq[3] = 0.0f; }  // class 255

        float m = fmaxf(fmaxf(vs[0], vs[1]), fmaxf(vs[2], vs[3]));
        #pragma unroll
        for (int off = 32; off > 0; off >>= 1)
            m = fmaxf(m, __shfl_xor(m, off, 64));

        float s1 = 0.0f, s2 = 0.0f, s3 = 0.0f;
        #pragma unroll
        for (int k = 0; k < 4; ++k) {
            s1 += __builtin_amdgcn_exp2f((vs[k] - m) * 1.44269504f);
            s2 += tq[k];
            s3 += tq[k] * vs[k];
        }
        #pragma unroll
        for (int off = 32; off > 0; off >>= 1) {
            s1 += __shfl_xor(s1, off, 64);
            s2 += __shfl_xor(s2, off, 64);
            s3 += __shfl_xor(s3, off, 64);
        }

        if (lane == 0) {
            const float s0   = (sbce[0] + sbce[1]) + (sbce[2] + sbce[3]);
            const float lse  = m + __builtin_amdgcn_logf(s1) * 0.69314718f;
            const float csum = -(s3 - lse * s2) / (s2 + 1e-10f);
            const float d    = pqrow[255] - tqrow[255];
            float4 o;
            o.x = s0; o.y = csum; o.z = d * d; o.w = 0.0f;
            *(float4*)(partials + (size_t)b * 4) = o;
        }
    }
}

__global__ __launch_bounds__(256) void finalize_kernel(
    const float* __restrict__ partials, float* __restrict__ out, int B) {
    const int tid = threadIdx.x;
    double s0 = 0.0, s1 = 0.0, s2 = 0.0;
    for (int r = tid; r < B; r += 256) {
        const float4 p = *(const float4*)(partials + (size_t)r * 4);
        s0 += (double)p.x; s1 += (double)p.y; s2 += (double)p.z;
    }
    #pragma unroll
    for (int off = 32; off > 0; off >>= 1) {
        s0 += __shfl_xor(s0, off, 64);
        s1 += __shfl_xor(s1, off, 64);
        s2 += __shfl_xor(s2, off, 64);
    }
    __shared__ double red[3][4];
    const int lane = tid & 63, w = tid >> 6;
    if (lane == 0) { red[0][w] = s0; red[1][w] = s1; red[2][w] = s2; }
    __syncthreads();
    if (tid == 0) {
        const double bs = red[0][0] + red[0][1] + red[0][2] + red[0][3];
        const double cs = red[1][0] + red[1][1] + red[1][2] + red[1][3];
        const double qs = red[2][0] + red[2][1] + red[2][2] + red[2][3];
        out[0] = (float)(bs / ((double)B * 4096.0));
        out[1] = (float)(200.0 * (cs / 255.0) + qs / (double)B);
    }
}

extern "C" void kernel_launch(void* const* d_in, const int* in_sizes, int n_in,
                              void* d_out, int out_size, void* d_ws, size_t ws_size,
                              hipStream_t stream) {
    const float* pred_legal     = (const float*)d_in[0];
    const float* pred_quality   = (const float*)d_in[1];
    const float* target_legal   = (const float*)d_in[2];
    const float* target_quality = (const float*)d_in[3];

    const int B = in_sizes[0] / 4096;   // 4096

    float* partials = (float*)d_ws;     // B * 4 floats

    criterion_rows<<<B, 256, 0, stream>>>(
        pred_legal, pred_quality, target_legal, target_quality, partials, B);
    finalize_kernel<<<1, 256, 0, stream>>>(partials, (float*)d_out, B);
}